// Round 8
// baseline (514.132 us; speedup 1.0000x reference)
//
#include <hip/hip_runtime.h>
#include <stdint.h>
#include <math.h>

typedef __attribute__((ext_vector_type(4))) float f32x4;
typedef __attribute__((ext_vector_type(8))) short short8;
typedef __attribute__((ext_vector_type(8))) _Float16 half8;
typedef unsigned short u16;
typedef unsigned int u32;
typedef unsigned char u8;

#define DEV static __device__ __forceinline__

DEV u32 fbits(float f) { union { float f; u32 u; } v; v.f = f; return v.u; }
DEV float bits2f(u32 u) { union { u32 u; float f; } v; v.u = u; return v.f; }

// bf16 round-to-nearest-even (for the split-fp32 proj GEMM)
DEV u16 f2bf_rne(float f) {
  u32 u = fbits(f);
  u32 r = u + 0x7fffu + ((u >> 16) & 1u);
  return (u16)(r >> 16);
}
DEV u16 f2bf_trunc(float f) { return (u16)(fbits(f) >> 16); }
DEV float bf2f(u16 h) { return bits2f(((u32)h) << 16); }
DEV void split2(float f, u16& h, u16& l) {
  h = f2bf_rne(f);
  float r = f - bf2f(h);
  l = f2bf_trunc(r);
}

// fp16 helpers
DEV u16 f2h(float f) { union { _Float16 h; u16 u; } v; v.h = (_Float16)f; return v.u; }
DEV float h2f(u16 u) { union { u16 u; _Float16 h; } v; v.u = u; return (float)v.h; }
DEV half8 as_h8(short8 s) { union { short8 s; half8 h; } u; u.s = s; return u.h; }
DEV uint2 pk4h(f32x4 v) {
  uint2 w;
  w.x = (u32)f2h(v[0]) | ((u32)f2h(v[1]) << 16);
  w.y = (u32)f2h(v[2]) | ((u32)f2h(v[3]) << 16);
  return w;
}

// software OCP e4m3fn encoder (RNE-ish; sat 448; used only in proj epilogues)
DEV u8 f32_to_e4m3(float f) {
  u32 sb = (fbits(f) >> 24) & 0x80u;
  float a = fabsf(f);
  if (!(a >= 0.001953125f)) return (u8)sb;     // <2^-9 (or NaN) -> +-0
  if (a > 448.f) return (u8)(sb | 0x7e);
  int e; float mant = frexpf(a, &e);           // a = mant*2^e, mant in [.5,1)
  int E = e + 6;                               // e4m3 biased exponent
  if (E <= 0) {                                // denormal: units of 2^-9
    int mi = (int)(a * 512.f + 0.5f);
    if (mi > 7) return (u8)(sb | 0x08);
    return (u8)(sb | mi);
  }
  int mi = (int)((mant * 2.f - 1.f) * 8.f + 0.5f);
  if (mi == 8) { mi = 0; ++E; }
  if (E > 15 || (E == 15 && mi > 6)) return (u8)(sb | 0x7e);
  return (u8)(sb | (E << 3) | mi);
}

DEV void gll16(const void* gsrc, char* ldsp) {
  __builtin_amdgcn_global_load_lds(
      (const __attribute__((address_space(1))) u32*)gsrc,
      (__attribute__((address_space(3))) u32*)ldsp,
      16, 0, 0);
}

DEV f32x4 mfma16(short8 a, short8 b, f32x4 c) {
  return __builtin_amdgcn_mfma_f32_16x16x32_bf16(a, b, c, 0, 0, 0);
}
DEV f32x4 mfmah(half8 a, half8 b, f32x4 c) {
  return __builtin_amdgcn_mfma_f32_16x16x32_f16(a, b, c, 0, 0, 0);
}
DEV f32x4 mfma8(long a, long b, f32x4 c) {
  return __builtin_amdgcn_mfma_f32_16x16x32_fp8_fp8(a, b, c, 0, 0, 0);
}

// ---------------------------------------------------------------------------
// K1: C = A[M][512]*B[N][512]^T fp32-emulated (split bf16, 3 MFMA). Epilogues:
// MODE 0 (q): o0 = fp16(5C) hi; o1 = fp16 residual lo; o2 = e4m3(hi value)
// MODE 2 (k): o0 = fp16(C) hi;  o2 = e4m3(4096 * fp16-residual)
// ---------------------------------------------------------------------------
template<int MODE>
__global__ __launch_bounds__(256, 1) void proj_qk(
    const float* __restrict__ A, const float* __restrict__ Bm,
    u16* __restrict__ o0, u16* __restrict__ o1, u8* __restrict__ o2,
    float scale)
{
  extern __shared__ char smem[];
  const int tid = threadIdx.x;
  const int lane = tid & 63, wv = tid >> 6;
  const int wm = wv & 1, wn = wv >> 1;
  const int lm = lane & 15, lg = lane >> 4;
  const int n0 = blockIdx.x * 128, m0 = blockIdx.y * 128;

  f32x4 acc[4][4] = {};

  for (int k0 = 0; k0 < 512; k0 += 64) {
    __syncthreads();
    #pragma unroll
    for (int i = 0; i < 8; ++i) {
      int c = i * 256 + tid;
      int row = c >> 4, c4 = c & 15;
      f32x4 av = *(const f32x4*)(A + (size_t)(m0 + row) * 512 + (k0 + c4 * 4));
      f32x4 bv = *(const f32x4*)(Bm + (size_t)(n0 + row) * 512 + (k0 + c4 * 4));
      int base = row * 128 + ((((c4 >> 1) ^ (row & 7)) << 4) + (c4 & 1) * 8);
      u16 ah[4], al[4], bh[4], bl[4];
      #pragma unroll
      for (int j = 0; j < 4; ++j) { split2(av[j], ah[j], al[j]); split2(bv[j], bh[j], bl[j]); }
      *(ushort4*)(smem +         base) = make_ushort4(ah[0], ah[1], ah[2], ah[3]);
      *(ushort4*)(smem + 16384 + base) = make_ushort4(al[0], al[1], al[2], al[3]);
      *(ushort4*)(smem + 32768 + base) = make_ushort4(bh[0], bh[1], bh[2], bh[3]);
      *(ushort4*)(smem + 49152 + base) = make_ushort4(bl[0], bl[1], bl[2], bl[3]);
    }
    __syncthreads();
    #pragma unroll
    for (int ks = 0; ks < 2; ++ks) {
      short8 fah[4], fal[4], fbh[4], fbl[4];
      #pragma unroll
      for (int t = 0; t < 4; ++t) {
        int ar = wm * 64 + t * 16 + lm;
        int ac = (((ks * 4 + lg) ^ (ar & 7)) << 4);
        fah[t] = *(const short8*)(smem +         ar * 128 + ac);
        fal[t] = *(const short8*)(smem + 16384 + ar * 128 + ac);
        int br = wn * 64 + t * 16 + lm;
        int bc = (((ks * 4 + lg) ^ (br & 7)) << 4);
        fbh[t] = *(const short8*)(smem + 32768 + br * 128 + bc);
        fbl[t] = *(const short8*)(smem + 49152 + br * 128 + bc);
      }
      #pragma unroll
      for (int mt = 0; mt < 4; ++mt)
        #pragma unroll
        for (int nt = 0; nt < 4; ++nt) {
          acc[mt][nt] = mfma16(fah[mt], fbh[nt], acc[mt][nt]);
          acc[mt][nt] = mfma16(fah[mt], fbl[nt], acc[mt][nt]);
          acc[mt][nt] = mfma16(fal[mt], fbh[nt], acc[mt][nt]);
        }
    }
  }
  #pragma unroll
  for (int mt = 0; mt < 4; ++mt)
    #pragma unroll
    for (int nt = 0; nt < 4; ++nt)
      #pragma unroll
      for (int i = 0; i < 4; ++i) {
        float v = acc[mt][nt][i] * scale;
        int m = m0 + wm * 64 + mt * 16 + lg * 4 + i;
        int n = n0 + wn * 64 + nt * 16 + lm;
        size_t idx = (size_t)m * 512 + n;
        u16 h = f2h(v);
        float res = v - h2f(h);
        o0[idx] = h;
        if (MODE == 0) {
          o1[idx] = f2h(res);
          o2[idx] = f32_to_e4m3(h2f(h));
        } else {
          o2[idx] = f32_to_e4m3(res * 4096.f);
        }
      }
}

// ---------------------------------------------------------------------------
// K1v: v^T = Wv * x^T, single-pass fp16 -> v_t[b][d][s]. (r7, LDS 32KB fixed)
// ---------------------------------------------------------------------------
__global__ __launch_bounds__(256, 1) void proj_v(
    const float* __restrict__ A, const float* __restrict__ Bm,
    u16* __restrict__ o0)
{
  extern __shared__ char smem[];
  const int tid = threadIdx.x;
  const int lane = tid & 63, wv = tid >> 6;
  const int wm = wv & 1, wn = wv >> 1;
  const int lm = lane & 15, lg = lane >> 4;
  const int n0 = blockIdx.x * 128, m0 = blockIdx.y * 128;

  f32x4 acc[4][4] = {};

  for (int k0 = 0; k0 < 512; k0 += 64) {
    __syncthreads();
    #pragma unroll
    for (int i = 0; i < 8; ++i) {
      int c = i * 256 + tid;
      int row = c >> 4, c4 = c & 15;
      f32x4 av = *(const f32x4*)(A + (size_t)(m0 + row) * 512 + (k0 + c4 * 4));
      f32x4 bv = *(const f32x4*)(Bm + (size_t)(n0 + row) * 512 + (k0 + c4 * 4));
      int base = row * 128 + ((c4 ^ (2 * (row & 7))) << 3);
      *(uint2*)(smem +         base) = pk4h(av);
      *(uint2*)(smem + 16384 + base) = pk4h(bv);
    }
    __syncthreads();
    #pragma unroll
    for (int ks = 0; ks < 2; ++ks) {
      half8 fa[4], fb[4];
      #pragma unroll
      for (int t = 0; t < 4; ++t) {
        int ar = wm * 64 + t * 16 + lm;
        fa[t] = as_h8(*(const short8*)(smem + ar * 128 + (((ks * 4 + lg) ^ (ar & 7)) << 4)));
        int br = wn * 64 + t * 16 + lm;
        fb[t] = as_h8(*(const short8*)(smem + 16384 + br * 128 + (((ks * 4 + lg) ^ (br & 7)) << 4)));
      }
      #pragma unroll
      for (int mt = 0; mt < 4; ++mt)
        #pragma unroll
        for (int nt = 0; nt < 4; ++nt)
          acc[mt][nt] = mfmah(fa[mt], fb[nt], acc[mt][nt]);
    }
  }
  #pragma unroll
  for (int mt = 0; mt < 4; ++mt)
    #pragma unroll
    for (int nt = 0; nt < 4; ++nt)
      #pragma unroll
      for (int i = 0; i < 4; ++i) {
        int m = m0 + wm * 64 + mt * 16 + lg * 4 + i;   // d
        int n = n0 + wn * 64 + nt * 16 + lm;           // global token
        size_t addr = ((size_t)(n >> 11) << 20) | ((size_t)m << 11) | (size_t)(n & 2047);
        o0[addr] = f2h(acc[mt][nt][i]);
      }
}

// ---------------------------------------------------------------------------
// K2: fused flash attention, 3-pass mixed fp16/fp8 QK. 4 waves, QBLK=64.
// Swapped QK^T, softmax lane-local. Passes: qh*kh (fp16), ql*kh (fp16, akh
// register-reuse), qh8*kl8x4096 (fp8 e4m3, merged *2^-12). Q/ql/q8 frags
// re-read from global per phase (L2-hot, kt-invariant). d-split PV with
// wave-interleaved rows; P through swizzled LDS. 8 phases/kt.
// LDS: K 2x40K (kh 32K + kl8 8K) | V 2x16K | P 8K | alpha 0.5K = 123.5KB
// ---------------------------------------------------------------------------
#define KHB(i)  ((i) * 40960)
#define KLB(i)  ((i) * 40960 + 32768)
#define VBUF(i) (81920 + (i) * 16384)
#define PB      114688
#define AB      122880
#define ALDS    123392

DEV void stageK(const u16* __restrict__ khp, const u8* __restrict__ klp,
                char* smem, int b, int kt, int c, int tid) {
  char* dh = smem + KHB(c & 1);
  char* dl = smem + KLB(c & 1);
  const size_t rbase = (size_t)(b * 2048 + kt * 64);
  #pragma unroll
  for (int j = 0; j < 4; ++j) {          // kh chunk [64k][128d] fp16 = 32KB
    int slot = j * 256 + tid;
    int r = slot >> 4, ch = slot & 15, sc = ch ^ (r & 7);
    gll16(khp + (rbase + r) * 512 + c * 128 + sc * 8, dh + slot * 16);
  }
  #pragma unroll
  for (int j = 0; j < 2; ++j) {          // kl8 chunk [64k][128d] fp8 = 8KB
    int slot = j * 256 + tid;
    int r = slot >> 3, ch = slot & 7, sc = ch ^ (r & 7);
    gll16(klp + (rbase + r) * 512 + c * 128 + sc * 16, dl + slot * 16);
  }
}
DEV void stageV(const u16* __restrict__ vp, char* smem, int b, int kt, int cv, int tid) {
  char* dst = smem + VBUF(cv & 1);
  #pragma unroll
  for (int j = 0; j < 4; ++j) {          // V chunk [128d][64k] fp16 = 16KB
    int slot = j * 256 + tid;
    int r = slot >> 3, ch = slot & 7, sc = ch ^ (r & 7);
    gll16(vp + ((size_t)b << 20) + (size_t)(cv * 128 + r) * 2048 + kt * 64 + sc * 8,
          dst + slot * 16);
  }
}

__global__ __launch_bounds__(256, 1) void attn_fused(
    const u16* __restrict__ qh_g, const u16* __restrict__ ql_g,
    const u8* __restrict__ q8_g, const u16* __restrict__ kh_g,
    const u8* __restrict__ kl8_g, const u16* __restrict__ v_g,
    float* __restrict__ out)
{
  extern __shared__ char smem[];
  const int tid = threadIdx.x;
  const int lane = tid & 63, wv = tid >> 6;
  const int lm = lane & 15, lg = lane >> 4;
  const int b = blockIdx.x, qt = blockIdx.y;   // batch fastest -> XCD-local K/V
  const int srow = wv * 16 + lm;               // lane's q (softmax row, local)
  const size_t qrow = (size_t)(b * 2048 + qt * 64 + srow);
  const u16* qph = qh_g + qrow * 512;
  const u16* qpl = ql_g + qrow * 512;
  const u8*  qp8 = q8_g + qrow * 512;

  stageK(kh_g, kl8_g, smem, b, 0, 0, tid);
  __syncthreads();

  float m = -3e38f, l = 0.f;
  f32x4 oacc[4][2][4] = {};

  for (int kt = 0; kt < 32; ++kt) {
    f32x4 sacc[4] = {};
    // ======== 4 QK phases (128 d each) ========
    #pragma unroll
    for (int dc = 0; dc < 4; ++dc) {
      if (dc < 3) stageK(kh_g, kl8_g, smem, b, kt, dc + 1, tid);
      else        stageV(v_g, smem, b, kt, 0, tid);
      __builtin_amdgcn_sched_barrier(0);
      // per-phase q fragments from global (L2-hot, kt-invariant addresses)
      half8 qhf[4], qlf[4];
      long  bq8[4];
      #pragma unroll
      for (int ks = 0; ks < 4; ++ks) {
        int doff = dc * 128 + ks * 32 + lg * 8;
        qhf[ks] = as_h8(*(const short8*)(qph + doff));
        qlf[ks] = as_h8(*(const short8*)(qpl + doff));
        bq8[ks] = *(const long*)(qp8 + doff);
      }
      const char* kb = smem + KHB(dc & 1);
      const char* lb = smem + KLB(dc & 1);
      __builtin_amdgcn_s_setprio(1);
      // pass1 + pass2 (akh reused in-register)
      #pragma unroll
      for (int ks = 0; ks < 4; ++ks)
        #pragma unroll
        for (int t4 = 0; t4 < 4; ++t4) {
          half8 akh = as_h8(*(const short8*)(
              kb + (t4 * 16 + lm) * 256 + (((ks * 4 + lg) ^ (lm & 7)) << 4)));
          sacc[t4] = mfmah(akh, qhf[ks], sacc[t4]);
          sacc[t4] = mfmah(akh, qlf[ks], sacc[t4]);
        }
      // pass3 (fp8): kl8 holds 4096*kl -> merge with 2^-12
      f32x4 s3[4] = {};
      #pragma unroll
      for (int ks = 0; ks < 4; ++ks)
        #pragma unroll
        for (int t4 = 0; t4 < 4; ++t4) {
          long akl = *(const long*)(
              lb + (t4 * 16 + lm) * 128 +
              ((((ks * 2 + (lg >> 1)) ^ (lm & 7)) << 4) + (lg & 1) * 8));
          s3[t4] = mfma8(akl, bq8[ks], s3[t4]);
        }
      __builtin_amdgcn_s_setprio(0);
      #pragma unroll
      for (int t4 = 0; t4 < 4; ++t4) {
        sacc[t4][0] += s3[t4][0] * 0.000244140625f;
        sacc[t4][1] += s3[t4][1] * 0.000244140625f;
        sacc[t4][2] += s3[t4][2] * 0.000244140625f;
        sacc[t4][3] += s3[t4][3] * 0.000244140625f;
      }
      if (dc == 3) {
        // ---- online softmax (lane-local in q), P + alpha to LDS
        float mx = fmaxf(fmaxf(fmaxf(sacc[0][0], sacc[0][1]), fmaxf(sacc[0][2], sacc[0][3])),
                         fmaxf(fmaxf(sacc[1][0], sacc[1][1]), fmaxf(sacc[1][2], sacc[1][3])));
        mx = fmaxf(mx, fmaxf(fmaxf(fmaxf(sacc[2][0], sacc[2][1]), fmaxf(sacc[2][2], sacc[2][3])),
                             fmaxf(fmaxf(sacc[3][0], sacc[3][1]), fmaxf(sacc[3][2], sacc[3][3]))));
        mx = fmaxf(mx, __shfl_xor(mx, 16, 64));
        mx = fmaxf(mx, __shfl_xor(mx, 32, 64));
        float alpha;
        if (__any(mx > m)) {          // exact rescale-skip
          float mn = fmaxf(m, mx);
          alpha = __expf(m - mn);
          m = mn;
          l *= alpha;
        } else {
          alpha = 1.0f;
        }
        float sm = 0.f;
        #pragma unroll
        for (int t4 = 0; t4 < 4; ++t4)
          #pragma unroll
          for (int i = 0; i < 4; ++i) {
            float p = __expf(sacc[t4][i] - m);
            sacc[t4][i] = p;
            sm += p;
          }
        sm += __shfl_xor(sm, 16, 64);
        sm += __shfl_xor(sm, 32, 64);
        l += sm;
        // P[srow][k], k=16*t4+4*lg+i, fp16, 8B-granule swizzle g^=2*(row&7)
        #pragma unroll
        for (int t4 = 0; t4 < 4; ++t4)
          *(uint2*)(smem + PB + srow * 128 + (((4 * t4 + lg) ^ (2 * (srow & 7))) << 3))
              = pk4h(sacc[t4]);
        if (lg == 0) *(float*)(smem + AB + srow * 4) = alpha;
      }
      __syncthreads();
    }
    // ======== 4 PV phases: wave wv owns rows wv*32..wv*32+31 of each chunk
    half8 pp[4][2];
    #pragma unroll
    for (int pc = 0; pc < 4; ++pc) {
      if (pc < 3) stageV(v_g, smem, b, kt, pc + 1, tid);
      else        stageK(kh_g, kl8_g, smem, b, (kt + 1) & 31, 0, tid);
      __builtin_amdgcn_sched_barrier(0);
      if (pc == 0) {
        float a4[4];
        #pragma unroll
        for (int st = 0; st < 4; ++st) {
          a4[st] = *(const float*)(smem + AB + (st * 16 + lm) * 4);
          #pragma unroll
          for (int ks = 0; ks < 2; ++ks)
            pp[st][ks] = as_h8(*(const short8*)(
                smem + PB + (st * 16 + lm) * 128 + (((ks * 4 + lg) ^ (lm & 7)) << 4)));
        }
        #pragma unroll
        for (int c2 = 0; c2 < 4; ++c2)
          #pragma unroll
          for (int dt = 0; dt < 2; ++dt)
            #pragma unroll
            for (int st = 0; st < 4; ++st) {
              oacc[c2][dt][st][0] *= a4[st]; oacc[c2][dt][st][1] *= a4[st];
              oacc[c2][dt][st][2] *= a4[st]; oacc[c2][dt][st][3] *= a4[st];
            }
      }
      const char* vb = smem + VBUF(pc & 1);
      __builtin_amdgcn_s_setprio(1);
      #pragma unroll
      for (int dt = 0; dt < 2; ++dt) {
        int vrow = wv * 32 + dt * 16 + lm;
        #pragma unroll
        for (int ks = 0; ks < 2; ++ks) {
          half8 av = as_h8(*(const short8*)(
              vb + vrow * 128 + (((ks * 4 + lg) ^ (lm & 7)) << 4)));
          #pragma unroll
          for (int st = 0; st < 4; ++st)
            oacc[pc][dt][st] = mfmah(av, pp[st][ks], oacc[pc][dt][st]);
        }
      }
      __builtin_amdgcn_s_setprio(0);
      __syncthreads();
    }
  }
  // ---- finalize: l broadcast, divide, coalesced O^T store
  if (lg == 0) *(float*)(smem + AB + srow * 4) = l;
  __syncthreads();
  float li[4];
  #pragma unroll
  for (int st = 0; st < 4; ++st)
    li[st] = 1.0f / *(const float*)(smem + AB + (st * 16 + lm) * 4);
  float* ob = out + ((size_t)b << 20) + qt * 64;
  #pragma unroll
  for (int pc = 0; pc < 4; ++pc)
    #pragma unroll
    for (int dt = 0; dt < 2; ++dt)
      #pragma unroll
      for (int st = 0; st < 4; ++st)
        #pragma unroll
        for (int i = 0; i < 4; ++i) {
          int d = pc * 128 + wv * 32 + dt * 16 + lg * 4 + i;
          ob[(size_t)d * 2048 + st * 16 + lm] = oacc[pc][dt][st][i] * li[st];
        }
}

// ---------------------------------------------------------------------------
extern "C" void kernel_launch(void* const* d_in, const int* in_sizes, int n_in,
                              void* d_out, int out_size, void* d_ws, size_t ws_size,
                              hipStream_t stream) {
  (void)in_sizes; (void)n_in; (void)out_size; (void)ws_size;
  const float* x  = (const float*)d_in[0];
  const float* Wk = (const float*)d_in[1];
  const float* Wq = (const float*)d_in[2];
  const float* Wv = (const float*)d_in[3];
  float* out = (float*)d_out;

  const size_t SZ = (size_t)16384 * 512;
  u16* qh  = (u16*)d_ws;           // fp16 [16384][512]
  u16* ql  = qh + SZ;              // fp16
  u16* kh  = ql + SZ;              // fp16
  u16* vt  = kh + SZ;              // fp16 [8][512][2048]
  u8*  q8  = (u8*)(vt + SZ);       // e4m3 [16384][512]
  u8*  kl8 = q8 + SZ;              // e4m3 (4096*kl)

  (void)hipFuncSetAttribute(reinterpret_cast<const void*>(&proj_qk<0>),
                            hipFuncAttributeMaxDynamicSharedMemorySize, 65536);
  (void)hipFuncSetAttribute(reinterpret_cast<const void*>(&proj_qk<2>),
                            hipFuncAttributeMaxDynamicSharedMemorySize, 65536);
  (void)hipFuncSetAttribute(reinterpret_cast<const void*>(&proj_v),
                            hipFuncAttributeMaxDynamicSharedMemorySize, 32768);
  (void)hipFuncSetAttribute(reinterpret_cast<const void*>(&attn_fused),
                            hipFuncAttributeMaxDynamicSharedMemorySize, ALDS);

  dim3 blk(256);
  // q = 5 * x @ Wq^T (scale folded so scores come out pre-scaled)
  proj_qk<0><<<dim3(4, 128), blk, 65536, stream>>>(x, Wq, qh, ql, q8, 5.0f);
  proj_qk<2><<<dim3(4, 128), blk, 65536, stream>>>(x, Wk, kh, nullptr, kl8, 1.0f);
  proj_v    <<<dim3(128, 4), blk, 32768, stream>>>(Wv, x, vt);
  attn_fused<<<dim3(8, 32), blk, ALDS, stream>>>(qh, ql, q8, kh, kl8, vt, out);
}

// Round 9
// 494.936 us; speedup vs baseline: 1.0388x; 1.0388x over previous
//
#include <hip/hip_runtime.h>
#include <stdint.h>

typedef __attribute__((ext_vector_type(4))) float f32x4;
typedef __attribute__((ext_vector_type(8))) short short8;
typedef __attribute__((ext_vector_type(8))) _Float16 half8;
typedef unsigned short u16;
typedef unsigned int u32;
typedef unsigned char u8;

#define DEV static __device__ __forceinline__

DEV u32 fbits(float f) { union { float f; u32 u; } v; v.f = f; return v.u; }
DEV float bits2f(u32 u) { union { u32 u; float f; } v; v.u = u; return v.f; }

// bf16 round-to-nearest-even (for the split-fp32 proj GEMM)
DEV u16 f2bf_rne(float f) {
  u32 u = fbits(f);
  u32 r = u + 0x7fffu + ((u >> 16) & 1u);
  return (u16)(r >> 16);
}
DEV u16 f2bf_trunc(float f) { return (u16)(fbits(f) >> 16); }
DEV float bf2f(u16 h) { return bits2f(((u32)h) << 16); }
DEV void split2(float f, u16& h, u16& l) {
  h = f2bf_rne(f);
  float r = f - bf2f(h);
  l = f2bf_trunc(r);
}

// fp16 helpers
DEV u16 f2h(float f) { union { _Float16 h; u16 u; } v; v.h = (_Float16)f; return v.u; }
DEV float h2f(u16 u) { union { u16 u; _Float16 h; } v; v.u = u; return (float)v.h; }
DEV half8 as_h8(short8 s) { union { short8 s; half8 h; } u; u.s = s; return u.h; }
DEV uint2 pk4h(f32x4 v) {
  uint2 w;
  w.x = (u32)f2h(v[0]) | ((u32)f2h(v[1]) << 16);
  w.y = (u32)f2h(v[2]) | ((u32)f2h(v[3]) << 16);
  return w;
}

// fast branch-light OCP e4m3fn encoder (RNE; sat 448; subnormals handled)
DEV u8 f32_to_e4m3(float f) {
  u32 u = fbits(f);
  u32 s = (u >> 24) & 0x80u;
  u32 a = u & 0x7fffffffu;
  if (a >= 0x43e00000u) return (u8)(s | 0x7e);   // >=448 (or NaN) -> max
  if (a < 0x3a800000u) return (u8)s;             // < 2^-10 -> +-0
  int e = (int)(a >> 23);
  u32 man = (a & 0x7fffffu) | 0x800000u;
  int E = e - 127 + 7;
  int sh = (E >= 1) ? 20 : (21 - E);             // extra shift for subnormals
  u32 q = (man + ((1u << (sh - 1)) - 1u + ((man >> sh) & 1u))) >> sh;
  if (E < 1) E = 1;
  if (q >= 16) { q >>= 1; ++E; }
  if (E >= 16) return (u8)(s | 0x7e);
  u32 enc = (q >= 8) ? (((u32)E << 3) | (q - 8)) : q;
  return (u8)(s | enc);
}

DEV void gll16(const void* gsrc, char* ldsp) {
  __builtin_amdgcn_global_load_lds(
      (const __attribute__((address_space(1))) u32*)gsrc,
      (__attribute__((address_space(3))) u32*)ldsp,
      16, 0, 0);
}

DEV f32x4 mfma16(short8 a, short8 b, f32x4 c) {
  return __builtin_amdgcn_mfma_f32_16x16x32_bf16(a, b, c, 0, 0, 0);
}
DEV f32x4 mfmah(half8 a, half8 b, f32x4 c) {
  return __builtin_amdgcn_mfma_f32_16x16x32_f16(a, b, c, 0, 0, 0);
}
DEV f32x4 mfma8(long a, long b, f32x4 c) {
  return __builtin_amdgcn_mfma_f32_16x16x32_fp8_fp8(a, b, c, 0, 0, 0);
}

// ---------------------------------------------------------------------------
// K1: C = A[M][512]*B[N][512]^T fp32-emulated (split bf16, 3 MFMA). Epilogues:
// MODE 0 (q): o0=fp16(5C); o1=fp16 residual; o2=e4m3(fp16 value)  row-major
// MODE 2 (k): o0=fp16(C) row-major; o2=e4m3(4096*residual) FRAG-MAJOR:
//   o2[(((b*32+kt)*4+dc)*16 + ks*4+t4)*512 + lane*8 + j]
// ---------------------------------------------------------------------------
template<int MODE>
__global__ __launch_bounds__(256, 1) void proj_qk(
    const float* __restrict__ A, const float* __restrict__ Bm,
    u16* __restrict__ o0, u16* __restrict__ o1, u8* __restrict__ o2,
    float scale)
{
  extern __shared__ char smem[];
  const int tid = threadIdx.x;
  const int lane = tid & 63, wv = tid >> 6;
  const int wm = wv & 1, wn = wv >> 1;
  const int lm = lane & 15, lg = lane >> 4;
  const int n0 = blockIdx.x * 128, m0 = blockIdx.y * 128;

  f32x4 acc[4][4] = {};

  for (int k0 = 0; k0 < 512; k0 += 64) {
    __syncthreads();
    #pragma unroll
    for (int i = 0; i < 8; ++i) {
      int c = i * 256 + tid;
      int row = c >> 4, c4 = c & 15;
      f32x4 av = *(const f32x4*)(A + (size_t)(m0 + row) * 512 + (k0 + c4 * 4));
      f32x4 bv = *(const f32x4*)(Bm + (size_t)(n0 + row) * 512 + (k0 + c4 * 4));
      int base = row * 128 + ((((c4 >> 1) ^ (row & 7)) << 4) + (c4 & 1) * 8);
      u16 ah[4], al[4], bh[4], bl[4];
      #pragma unroll
      for (int j = 0; j < 4; ++j) { split2(av[j], ah[j], al[j]); split2(bv[j], bh[j], bl[j]); }
      *(ushort4*)(smem +         base) = make_ushort4(ah[0], ah[1], ah[2], ah[3]);
      *(ushort4*)(smem + 16384 + base) = make_ushort4(al[0], al[1], al[2], al[3]);
      *(ushort4*)(smem + 32768 + base) = make_ushort4(bh[0], bh[1], bh[2], bh[3]);
      *(ushort4*)(smem + 49152 + base) = make_ushort4(bl[0], bl[1], bl[2], bl[3]);
    }
    __syncthreads();
    #pragma unroll
    for (int ks = 0; ks < 2; ++ks) {
      short8 fah[4], fal[4], fbh[4], fbl[4];
      #pragma unroll
      for (int t = 0; t < 4; ++t) {
        int ar = wm * 64 + t * 16 + lm;
        int ac = (((ks * 4 + lg) ^ (ar & 7)) << 4);
        fah[t] = *(const short8*)(smem +         ar * 128 + ac);
        fal[t] = *(const short8*)(smem + 16384 + ar * 128 + ac);
        int br = wn * 64 + t * 16 + lm;
        int bc = (((ks * 4 + lg) ^ (br & 7)) << 4);
        fbh[t] = *(const short8*)(smem + 32768 + br * 128 + bc);
        fbl[t] = *(const short8*)(smem + 49152 + br * 128 + bc);
      }
      #pragma unroll
      for (int mt = 0; mt < 4; ++mt)
        #pragma unroll
        for (int nt = 0; nt < 4; ++nt) {
          acc[mt][nt] = mfma16(fah[mt], fbh[nt], acc[mt][nt]);
          acc[mt][nt] = mfma16(fah[mt], fbl[nt], acc[mt][nt]);
          acc[mt][nt] = mfma16(fal[mt], fbh[nt], acc[mt][nt]);
        }
    }
  }
  #pragma unroll
  for (int mt = 0; mt < 4; ++mt)
    #pragma unroll
    for (int nt = 0; nt < 4; ++nt)
      #pragma unroll
      for (int i = 0; i < 4; ++i) {
        float v = acc[mt][nt][i] * scale;
        int m = m0 + wm * 64 + mt * 16 + lg * 4 + i;
        int n = n0 + wn * 64 + nt * 16 + lm;
        size_t idx = (size_t)m * 512 + n;
        u16 h = f2h(v);
        float res = v - h2f(h);
        o0[idx] = h;
        if (MODE == 0) {
          o1[idx] = f2h(res);
          o2[idx] = f32_to_e4m3(h2f(h));
        } else {
          int b2 = m >> 11, sL = m & 2047;
          int kt = sL >> 6, t4s = (sL >> 4) & 3, lma = sL & 15;
          int dc = n >> 7, ks = (n >> 5) & 3, lga = (n >> 3) & 3, j = n & 7;
          size_t fidx = (((size_t)((b2 * 32 + kt) * 4 + dc)) * 16 + (ks * 4 + t4s)) * 512
                        + (size_t)(lga * 16 + lma) * 8 + j;
          o2[fidx] = f32_to_e4m3(res * 4096.f);
        }
      }
}

// ---------------------------------------------------------------------------
// K1v: v^T = Wv * x^T, single-pass fp16 -> v_t[b][d][s]. (r8, 32KB LDS)
// ---------------------------------------------------------------------------
__global__ __launch_bounds__(256, 1) void proj_v(
    const float* __restrict__ A, const float* __restrict__ Bm,
    u16* __restrict__ o0)
{
  extern __shared__ char smem[];
  const int tid = threadIdx.x;
  const int lane = tid & 63, wv = tid >> 6;
  const int wm = wv & 1, wn = wv >> 1;
  const int lm = lane & 15, lg = lane >> 4;
  const int n0 = blockIdx.x * 128, m0 = blockIdx.y * 128;

  f32x4 acc[4][4] = {};

  for (int k0 = 0; k0 < 512; k0 += 64) {
    __syncthreads();
    #pragma unroll
    for (int i = 0; i < 8; ++i) {
      int c = i * 256 + tid;
      int row = c >> 4, c4 = c & 15;
      f32x4 av = *(const f32x4*)(A + (size_t)(m0 + row) * 512 + (k0 + c4 * 4));
      f32x4 bv = *(const f32x4*)(Bm + (size_t)(n0 + row) * 512 + (k0 + c4 * 4));
      int base = row * 128 + ((c4 ^ (2 * (row & 7))) << 3);
      *(uint2*)(smem +         base) = pk4h(av);
      *(uint2*)(smem + 16384 + base) = pk4h(bv);
    }
    __syncthreads();
    #pragma unroll
    for (int ks = 0; ks < 2; ++ks) {
      half8 fa[4], fb[4];
      #pragma unroll
      for (int t = 0; t < 4; ++t) {
        int ar = wm * 64 + t * 16 + lm;
        fa[t] = as_h8(*(const short8*)(smem + ar * 128 + (((ks * 4 + lg) ^ (ar & 7)) << 4)));
        int br = wn * 64 + t * 16 + lm;
        fb[t] = as_h8(*(const short8*)(smem + 16384 + br * 128 + (((ks * 4 + lg) ^ (br & 7)) << 4)));
      }
      #pragma unroll
      for (int mt = 0; mt < 4; ++mt)
        #pragma unroll
        for (int nt = 0; nt < 4; ++nt)
          acc[mt][nt] = mfmah(fa[mt], fb[nt], acc[mt][nt]);
    }
  }
  #pragma unroll
  for (int mt = 0; mt < 4; ++mt)
    #pragma unroll
    for (int nt = 0; nt < 4; ++nt)
      #pragma unroll
      for (int i = 0; i < 4; ++i) {
        int m = m0 + wm * 64 + mt * 16 + lg * 4 + i;
        int n = n0 + wn * 64 + nt * 16 + lm;
        size_t addr = ((size_t)(n >> 11) << 20) | ((size_t)m << 11) | (size_t)(n & 2047);
        o0[addr] = f2h(acc[mt][nt][i]);
      }
}

// ---------------------------------------------------------------------------
// K2: fused flash attention. 4 waves, QBLK=64, swapped QK^T, 3-pass
// fp16/fp16/fp8 (r8-validated numerics). Q-hi/lo in REGISTERS (loaded once,
// kt-invariant); q8 in LDS (32KB static, swizzled). kl8 frag-major ->
// linear staging + conflict-free reads. 8 phases/kt, 4 rotating 24KB bufs,
// ONE raw s_barrier/phase + counted vmcnt(6/4). d-split PV via P-LDS.
// LDS: 4x24K bufs | P 8K | alpha 256B | q8 32K = 136.3KB
// ---------------------------------------------------------------------------
#define BUF(i) ((i) * 24576)
#define PB     98304
#define AB     106496
#define Q8B    106752
#define ALDS   139520

DEV void stageK(const u16* __restrict__ khp, const u8* __restrict__ klp,
                char* smem, int b, int kt, int c, int tid, int bufi) {
  char* dh = smem + BUF(bufi);
  char* dl = dh + 16384;
  const size_t rb = (size_t)(b * 2048 + kt * 64);
  #pragma unroll
  for (int j = 0; j < 4; ++j) {          // kh chunk [64k][128d] fp16, swizzled
    int slot = j * 256 + tid;
    int r = slot >> 4, ch = slot & 15, sc = ch ^ (r & 7);
    gll16(khp + (rb + r) * 512 + c * 128 + sc * 8, dh + slot * 16);
  }
  const size_t kb8 = ((size_t)((b * 32 + kt) * 4 + c)) * 8192;
  #pragma unroll
  for (int j = 0; j < 2; ++j) {          // kl8 chunk, frag-major: LINEAR copy
    int slot = j * 256 + tid;
    gll16(klp + kb8 + slot * 16, dl + slot * 16);
  }
}
DEV void stageV(const u16* __restrict__ vp, char* smem, int b, int kt, int cv,
                int tid, int bufi) {
  char* dst = smem + BUF(bufi);
  #pragma unroll
  for (int j = 0; j < 4; ++j) {          // V chunk [128d][64k] fp16, swizzled
    int slot = j * 256 + tid;
    int r = slot >> 3, ch = slot & 7, sc = ch ^ (r & 7);
    gll16(vp + ((size_t)b << 20) + (size_t)(cv * 128 + r) * 2048 + kt * 64 + sc * 8,
          dst + slot * 16);
  }
}

__global__ __launch_bounds__(256, 1) void attn_fused(
    const u16* __restrict__ qh_g, const u16* __restrict__ ql_g,
    const u8* __restrict__ q8_g, const u16* __restrict__ kh_g,
    const u8* __restrict__ kl8_g, const u16* __restrict__ v_g,
    float* __restrict__ out)
{
  extern __shared__ char smem[];
  const int tid = threadIdx.x;
  const int lane = tid & 63, wv = tid >> 6;
  const int lm = lane & 15, lg = lane >> 4;
  const int b = blockIdx.x, qt = blockIdx.y;   // batch fastest -> XCD-local K/V
  const int srow = wv * 16 + lm;               // lane's q col (softmax row)
  const size_t qrow0 = (size_t)(b * 2048 + qt * 64);

  // ---- Q-hi / Q-lo to registers (kt-invariant, loaded ONCE)
  half8 qhr[16], qlr[16];
  {
    const u16* qph = qh_g + (qrow0 + srow) * 512;
    const u16* qpl = ql_g + (qrow0 + srow) * 512;
    #pragma unroll
    for (int j = 0; j < 16; ++j) {
      qhr[j] = as_h8(*(const short8*)(qph + j * 32 + lg * 8));
      qlr[j] = as_h8(*(const short8*)(qpl + j * 32 + lg * 8));
    }
  }
  // ---- q8 [64][512B] into LDS, 16B-chunk swizzle ch^(r&7)
  #pragma unroll
  for (int it = 0; it < 8; ++it) {
    int slot = it * 256 + tid;
    int r = slot >> 5, ch = slot & 31, sc = ch ^ (r & 7);
    gll16(q8_g + (qrow0 + r) * 512 + sc * 16, smem + Q8B + slot * 16);
  }
  stageK(kh_g, kl8_g, smem, b, 0, 0, tid, 0);
  asm volatile("s_waitcnt vmcnt(0)" ::: "memory");
  __syncthreads();

  float m = -3e38f, l = 0.f;
  f32x4 oacc[4][2][4] = {};
  half8 pp[4][2];

  for (int kt = 0; kt < 32; ++kt) {
    f32x4 sacc[4] = {};
    #pragma unroll
    for (int p = 0; p < 8; ++p) {
      // ---- stage phase p+1 into buf (p+1)&3
      if (p < 3)      stageK(kh_g, kl8_g, smem, b, kt, p + 1, tid, (p + 1) & 3);
      else if (p < 7) stageV(v_g, smem, b, kt, p - 3, tid, (p + 1) & 3);
      else            stageK(kh_g, kl8_g, smem, b, (kt + 1) & 31, 0, tid, 0);
      // ---- wait stage(p) complete (keep stage(p+1) in flight), sync
      if (p < 3 || p == 7) asm volatile("s_waitcnt vmcnt(6)" ::: "memory");
      else                 asm volatile("s_waitcnt vmcnt(4)" ::: "memory");
      __builtin_amdgcn_sched_barrier(0);
      __builtin_amdgcn_s_barrier();
      __builtin_amdgcn_sched_barrier(0);
      const char* bufp = smem + BUF(p & 3);
      if (p < 4) {
        // ======== QK phase dc=p: 3-pass over 128 d ========
        const char* lb = bufp + 16384;
        f32x4 s3[4] = {};
        #pragma unroll
        for (int ks = 0; ks < 4; ++ks) {
          half8 bqh = qhr[p * 4 + ks];
          half8 bql = qlr[p * 4 + ks];
          long bq8 = *(const long*)(
              smem + Q8B + srow * 512 +
              (((p * 16 + ks * 4 + lg) ^ ((srow & 7) << 1)) << 3));
          #pragma unroll
          for (int t4 = 0; t4 < 4; ++t4) {
            half8 akh = as_h8(*(const short8*)(
                bufp + (t4 * 16 + lm) * 256 + (((ks * 4 + lg) ^ (lm & 7)) << 4)));
            sacc[t4] = mfmah(akh, bqh, sacc[t4]);
            sacc[t4] = mfmah(akh, bql, sacc[t4]);
            long akl = *(const long*)(lb + (ks * 4 + t4) * 512 + lane * 8);
            s3[t4] = mfma8(akl, bq8, s3[t4]);
          }
        }
        #pragma unroll
        for (int t4 = 0; t4 < 4; ++t4) {
          sacc[t4][0] += s3[t4][0] * 0.000244140625f;
          sacc[t4][1] += s3[t4][1] * 0.000244140625f;
          sacc[t4][2] += s3[t4][2] * 0.000244140625f;
          sacc[t4][3] += s3[t4][3] * 0.000244140625f;
        }
        if (p == 3) {
          // ---- online softmax (lane-local), P + alpha to LDS
          float mx = fmaxf(fmaxf(fmaxf(sacc[0][0], sacc[0][1]), fmaxf(sacc[0][2], sacc[0][3])),
                           fmaxf(fmaxf(sacc[1][0], sacc[1][1]), fmaxf(sacc[1][2], sacc[1][3])));
          mx = fmaxf(mx, fmaxf(fmaxf(fmaxf(sacc[2][0], sacc[2][1]), fmaxf(sacc[2][2], sacc[2][3])),
                               fmaxf(fmaxf(sacc[3][0], sacc[3][1]), fmaxf(sacc[3][2], sacc[3][3]))));
          mx = fmaxf(mx, __shfl_xor(mx, 16, 64));
          mx = fmaxf(mx, __shfl_xor(mx, 32, 64));
          float alpha;
          if (__any(mx > m)) {        // exact rescale-skip
            float mn = fmaxf(m, mx);
            alpha = __expf(m - mn);
            m = mn;
            l *= alpha;
          } else {
            alpha = 1.0f;
          }
          float sm = 0.f;
          #pragma unroll
          for (int t4 = 0; t4 < 4; ++t4)
            #pragma unroll
            for (int i = 0; i < 4; ++i) {
              float pv = __expf(sacc[t4][i] - m);
              sacc[t4][i] = pv;
              sm += pv;
            }
          sm += __shfl_xor(sm, 16, 64);
          sm += __shfl_xor(sm, 32, 64);
          l += sm;
          #pragma unroll
          for (int t4 = 0; t4 < 4; ++t4)
            *(uint2*)(smem + PB + srow * 128 + (((4 * t4 + lg) ^ (2 * (srow & 7))) << 3))
                = pk4h(sacc[t4]);
          if (lg == 0) *(float*)(smem + AB + srow * 4) = alpha;
          asm volatile("s_waitcnt lgkmcnt(0)" ::: "memory");
          __builtin_amdgcn_sched_barrier(0);
        }
      } else {
        // ======== PV phase pc=p-4: wave wv owns rows wv*32..+32 ========
        const int pc = p - 4;
        if (pc == 0) {
          float a4[4];
          #pragma unroll
          for (int st = 0; st < 4; ++st) {
            a4[st] = *(const float*)(smem + AB + (st * 16 + lm) * 4);
            #pragma unroll
            for (int ks = 0; ks < 2; ++ks)
              pp[st][ks] = as_h8(*(const short8*)(
                  smem + PB + (st * 16 + lm) * 128 + (((ks * 4 + lg) ^ (lm & 7)) << 4)));
          }
          #pragma unroll
          for (int c2 = 0; c2 < 4; ++c2)
            #pragma unroll
            for (int dt = 0; dt < 2; ++dt)
              #pragma unroll
              for (int st = 0; st < 4; ++st) {
                oacc[c2][dt][st][0] *= a4[st]; oacc[c2][dt][st][1] *= a4[st];
                oacc[c2][dt][st][2] *= a4[st]; oacc[c2][dt][st][3] *= a4[st];
              }
        }
        #pragma unroll
        for (int dt = 0; dt < 2; ++dt) {
          int vrow = wv * 32 + dt * 16 + lm;
          #pragma unroll
          for (int ks = 0; ks < 2; ++ks) {
            half8 av = as_h8(*(const short8*)(
                bufp + vrow * 128 + (((ks * 4 + lg) ^ (lm & 7)) << 4)));
            #pragma unroll
            for (int st = 0; st < 4; ++st)
              oacc[pc][dt][st] = mfmah(av, pp[st][ks], oacc[pc][dt][st]);
          }
        }
      }
    }
  }
  // ---- finalize: drain, l broadcast, divide, coalesced O^T store
  asm volatile("s_waitcnt vmcnt(0)" ::: "memory");
  __syncthreads();
  if (lg == 0) *(float*)(smem + AB + srow * 4) = l;
  __syncthreads();
  float li[4];
  #pragma unroll
  for (int st = 0; st < 4; ++st)
    li[st] = 1.0f / *(const float*)(smem + AB + (st * 16 + lm) * 4);
  float* ob = out + ((size_t)b << 20) + qt * 64;
  #pragma unroll
  for (int pc = 0; pc < 4; ++pc)
    #pragma unroll
    for (int dt = 0; dt < 2; ++dt)
      #pragma unroll
      for (int st = 0; st < 4; ++st)
        #pragma unroll
        for (int i = 0; i < 4; ++i) {
          int d = pc * 128 + wv * 32 + dt * 16 + lg * 4 + i;
          ob[(size_t)d * 2048 + st * 16 + lm] = oacc[pc][dt][st][i] * li[st];
        }
}

// ---------------------------------------------------------------------------
extern "C" void kernel_launch(void* const* d_in, const int* in_sizes, int n_in,
                              void* d_out, int out_size, void* d_ws, size_t ws_size,
                              hipStream_t stream) {
  (void)in_sizes; (void)n_in; (void)out_size; (void)ws_size;
  const float* x  = (const float*)d_in[0];
  const float* Wk = (const float*)d_in[1];
  const float* Wq = (const float*)d_in[2];
  const float* Wv = (const float*)d_in[3];
  float* out = (float*)d_out;

  const size_t SZ = (size_t)16384 * 512;
  u16* qh  = (u16*)d_ws;           // fp16 [16384][512]
  u16* ql  = qh + SZ;              // fp16
  u16* kh  = ql + SZ;              // fp16
  u16* vt  = kh + SZ;              // fp16 [8][512][2048]
  u8*  q8  = (u8*)(vt + SZ);       // e4m3 row-major
  u8*  kl8 = q8 + SZ;              // e4m3 (4096*kl), frag-major

  (void)hipFuncSetAttribute(reinterpret_cast<const void*>(&proj_qk<0>),
                            hipFuncAttributeMaxDynamicSharedMemorySize, 65536);
  (void)hipFuncSetAttribute(reinterpret_cast<const void*>(&proj_qk<2>),
                            hipFuncAttributeMaxDynamicSharedMemorySize, 65536);
  (void)hipFuncSetAttribute(reinterpret_cast<const void*>(&proj_v),
                            hipFuncAttributeMaxDynamicSharedMemorySize, 32768);
  (void)hipFuncSetAttribute(reinterpret_cast<const void*>(&attn_fused),
                            hipFuncAttributeMaxDynamicSharedMemorySize, ALDS);

  dim3 blk(256);
  // q = 5 * x @ Wq^T (scale folded so scores come out pre-scaled)
  proj_qk<0><<<dim3(4, 128), blk, 65536, stream>>>(x, Wq, qh, ql, q8, 5.0f);
  proj_qk<2><<<dim3(4, 128), blk, 65536, stream>>>(x, Wk, kh, nullptr, kl8, 1.0f);
  proj_v    <<<dim3(128, 4), blk, 32768, stream>>>(Wv, x, vt);
  attn_fused<<<dim3(8, 32), blk, ALDS, stream>>>(qh, ql, q8, kh, kl8, vt, out);
}